// Round 3
// baseline (994.279 us; speedup 1.0000x reference)
//
#include <hip/hip_runtime.h>
#include <hip/hip_bf16.h>
#include <stdint.h>

#define S_DIM 2048
#define B_DIM 16
#define H2_DIM 2048
#define V_DIM 1024
#define M_DIM (S_DIM * B_DIM)   // 32768
#define K_HALF 2048
#define K_TOT 4096

typedef __attribute__((ext_vector_type(8))) short s16x8;   // 8 bf16 (4 VGPRs) MFMA frag
typedef __attribute__((ext_vector_type(4))) float f32x4;   // MFMA accumulator

// fp32 -> bf16 round-to-nearest-even (scalar, used in transposeB only)
__device__ __forceinline__ uint16_t f2bf(float f) {
    union { float f; uint32_t u; } c; c.f = f;
    uint32_t u = c.u;
    u += 0x7fffu + ((u >> 16) & 1u);
    return (uint16_t)(u >> 16);
}

// pack 2 fp32 -> 2 bf16 (round-to-nearest), 3 VALU ops: 2 adds + 1 v_perm_b32
__device__ __forceinline__ uint32_t pack_bf16_rn(float a, float b) {
    union { float f; uint32_t u; } ca, cb; ca.f = a; cb.f = b;
    uint32_t ua = ca.u + 0x8000u;
    uint32_t ub = cb.u + 0x8000u;
    return __builtin_amdgcn_perm(ub, ua, 0x07060302u);
}

__device__ __forceinline__ s16x8 pack8(float4 x, float4 y) {
    union { uint4 u; s16x8 v; } r;
    r.u = make_uint4(pack_bf16_rn(x.x, x.y), pack_bf16_rn(x.z, x.w),
                     pack_bf16_rn(y.x, y.y), pack_bf16_rn(y.z, y.w));
    return r.v;
}

__device__ __forceinline__ float fast_tanh(float x) {
    float e = __expf(2.0f * x);
    return 1.0f - 2.0f / (e + 1.0f);
}

// async global->LDS, 16B per lane. LDS dest is wave-uniform base + lane*16.
__device__ __forceinline__ void gload_lds16(const void* g, void* l) {
    __builtin_amdgcn_global_load_lds(
        (__attribute__((address_space(1))) void*)(uintptr_t)g,
        (__attribute__((address_space(3))) void*)(uint32_t)(uintptr_t)l,
        16, 0, 0);
}

// ------------- transpose+convert Ww/Wz [K][V] fp32 -> B^T [V][K] bf16 -------------
__global__ void transposeB(const float* __restrict__ Ww, const float* __restrict__ Wz,
                           uint16_t* __restrict__ B1, uint16_t* __restrict__ B2) {
    __shared__ float tile[32][33];
    const float* src = blockIdx.z ? Wz : Ww;
    uint16_t* dst = blockIdx.z ? B2 : B1;
    int k0 = blockIdx.x * 32, v0 = blockIdx.y * 32;
    int tv = threadIdx.x & 31, tk = threadIdx.x >> 5;  // tk in 0..7
#pragma unroll
    for (int r = 0; r < 4; r++) {
        int k = tk * 4 + r;
        tile[k][tv] = src[(size_t)(k0 + k) * V_DIM + v0 + tv];
    }
    __syncthreads();
#pragma unroll
    for (int r = 0; r < 4; r++) {
        int v = tk * 4 + r;
        dst[(size_t)(v0 + v) * K_HALF + k0 + tv] = f2bf(tile[tv][v]);
    }
}

// ---------------------------------- fused GEMM ----------------------------------
// 128(m) x 128(n) tile, 4 waves each 32m x 128n. A fp32 loaded DIRECT global->reg
// fragments (no LDS) and packed to bf16; B bf16 double-buffered in LDS via async
// DMA with ONE barrier per K-step (prefetch stays in flight across compute).
// Epilogue: u[m] += sum_n tanh(C[m,n]+bias[n]) * Vw[n]
__global__ __launch_bounds__(256, 3) void gemm_kernel(
    const float* __restrict__ F1, const float* __restrict__ F2,
    const uint16_t* __restrict__ B1, const uint16_t* __restrict__ B2,
    const float* __restrict__ bw, const float* __restrict__ bz,
    const float* __restrict__ wa_p, const float* __restrict__ Vw,
    float* __restrict__ u) {
    __shared__ __align__(16) uint16_t lB[2][128 * 64];   // 2 x 16 KB double buffer

    const int tid = threadIdx.x;
    const int lane = tid & 63;
    const int wv = tid >> 6;                  // wave 0..3; wave-tile rows wv*32..+31
    // XCD swizzle: all 8 n-tiles of one m-tile land on the same XCD (id mod 8),
    // spaced 8 apart in dispatch order -> A K-slices stay L2-resident.
    const int id = blockIdx.x;                // grid = 2048 = 256 m-tiles x 8 n-tiles
    const int nBase = ((id >> 3) & 7) * 128;
    const int mBase = ((id & 7) + ((id >> 6) << 3)) * 128;
    const int col = lane & 15, quad = lane >> 4;
    const int lr = lane >> 3;                 // B staging: row within 8-row group
    const int lc = lane & 7;                  // LDS chunk slot
    const int cg = lc ^ lr;                   // swizzled global chunk

    f32x4 acc[2][8] = {};

    // Per-lane A row base pointers (rows m0 = wv*32+col, m1 = m0+16), both K-halves.
    const size_t rowOff = (size_t)(mBase + wv * 32 + col) * K_HALF + quad * 8;
    const float* a0h[2] = { F1 + rowOff, F2 + rowOff };
    const float* a1h[2] = { F1 + rowOff + (size_t)16 * K_HALF, F2 + rowOff + (size_t)16 * K_HALF };

    // prologue: stage B for step 0 into buffer 0
#pragma unroll
    for (int j = 0; j < 4; j++) {
        const int rb = wv * 32 + j * 8;
        gload_lds16(B1 + (size_t)(nBase + rb + lr) * K_HALF + cg * 8, &lB[0][rb * 64]);
    }

#pragma unroll 2
    for (int s = 0; s < 64; s++) {
        const int kb = s * 64;
        const int kcol = kb & (K_HALF - 1);
        const int half = (kb < K_HALF) ? 0 : 1;

        __syncthreads();   // drains vmcnt: step-s DMA (issued ~600 cyc ago) + own loads

        // A direct loads for this step (8x float4; 16 cache lines each, 4 lanes/line)
        const float* a0 = a0h[half] + kcol;
        const float* a1 = a1h[half] + kcol;
        float4 x00 = ((const float4*)a0)[0];
        float4 y00 = ((const float4*)a0)[1];
        float4 x10 = ((const float4*)a1)[0];
        float4 y10 = ((const float4*)a1)[1];
        float4 x01 = ((const float4*)(a0 + 32))[0];
        float4 y01 = ((const float4*)(a0 + 32))[1];
        float4 x11 = ((const float4*)(a1 + 32))[0];
        float4 y11 = ((const float4*)(a1 + 32))[1];

        // issue NEXT step's B DMA into the other buffer; stays in flight during compute
        if (s + 1 < 64) {
            const int kb2 = kb + 64;
            const int kcol2 = kb2 & (K_HALF - 1);
            const uint16_t* Bb = (kb2 < K_HALF) ? B1 : B2;
            uint16_t* dst = lB[(s + 1) & 1];
#pragma unroll
            for (int j = 0; j < 4; j++) {
                const int rb = wv * 32 + j * 8;
                gload_lds16(Bb + (size_t)(nBase + rb + lr) * K_HALF + kcol2 + cg * 8, &dst[rb * 64]);
            }
        }

        const uint16_t* lb = lB[s & 1];
        s16x8 af[2][2];
        af[0][0] = pack8(x00, y00);
        af[1][0] = pack8(x10, y10);
        af[0][1] = pack8(x01, y01);
        af[1][1] = pack8(x11, y11);

#pragma unroll
        for (int kk = 0; kk < 2; kk++) {
            s16x8 bf[8];
            const int cidx = kk * 4 + quad;
#pragma unroll
            for (int j = 0; j < 8; j++) {
                int n = j * 16 + col;
                bf[j] = *(const s16x8*)&lb[n * 64 + ((cidx ^ (n & 7)) << 3)];
            }
#pragma unroll
            for (int j = 0; j < 8; j++) {
                acc[0][j] = __builtin_amdgcn_mfma_f32_16x16x32_bf16(af[0][kk], bf[j], acc[0][j], 0, 0, 0);
                acc[1][j] = __builtin_amdgcn_mfma_f32_16x16x32_bf16(af[1][kk], bf[j], acc[1][j], 0, 0, 0);
            }
        }
    }

    // ---- fused epilogue: bias + tanh + Vw-dot, reduce 128 n-cols -> u[m] ----
    const float wa05 = wa_p[0] * 0.5f;
    float biasv[8], vwv[8];
#pragma unroll
    for (int j = 0; j < 8; j++) {
        int n = nBase + j * 16 + col;
        biasv[j] = bw[n] + bz[n] + wa05;
        vwv[j] = Vw[n];
    }
#pragma unroll
    for (int i = 0; i < 2; i++) {
#pragma unroll
        for (int r = 0; r < 4; r++) {
            float sv = 0.f;
#pragma unroll
            for (int j = 0; j < 8; j++) {
                float xv = acc[i][j][r] + biasv[j];
                sv += fast_tanh(xv) * vwv[j];
            }
            // reduce across the 16 n-cols held by this quad group (D: col=lane&15)
            sv += __shfl_xor(sv, 8);
            sv += __shfl_xor(sv, 4);
            sv += __shfl_xor(sv, 2);
            sv += __shfl_xor(sv, 1);
            if (col == 0)
                atomicAdd(&u[mBase + wv * 32 + i * 16 + quad * 4 + r], sv);
        }
    }
}

// ------------------- softmax over S per batch, in-place on u=d_out -------------------
__global__ void softmax_kernel(float* __restrict__ u) {
    const int b = blockIdx.x;
    const int t = threadIdx.x;  // 256 threads, 8 s-values each
    __shared__ float redm[4], reds[4];
    float v[8];
    float mx = -1e30f;
#pragma unroll
    for (int k = 0; k < 8; k++) {
        v[k] = u[(size_t)(t + k * 256) * B_DIM + b];
        mx = fmaxf(mx, v[k]);
    }
#pragma unroll
    for (int off = 32; off >= 1; off >>= 1) mx = fmaxf(mx, __shfl_xor(mx, off));
    if ((t & 63) == 0) redm[t >> 6] = mx;
    __syncthreads();
    mx = fmaxf(fmaxf(redm[0], redm[1]), fmaxf(redm[2], redm[3]));
    float s = 0.f;
#pragma unroll
    for (int k = 0; k < 8; k++) {
        v[k] = __expf(v[k] - mx);
        s += v[k];
    }
#pragma unroll
    for (int off = 32; off >= 1; off >>= 1) s += __shfl_xor(s, off);
    if ((t & 63) == 0) reds[t >> 6] = s;
    __syncthreads();
    s = reds[0] + reds[1] + reds[2] + reds[3];
    float inv = 1.0f / s;
#pragma unroll
    for (int k = 0; k < 8; k++)
        u[(size_t)(t + k * 256) * B_DIM + b] = v[k] * inv;
}

extern "C" void kernel_launch(void* const* d_in, const int* in_sizes, int n_in,
                              void* d_out, int out_size, void* d_ws, size_t ws_size,
                              hipStream_t stream) {
    const float* hidden = (const float*)d_in[0];
    const float* z = (const float*)d_in[1];
    const float* Ww = (const float*)d_in[2];
    const float* bw = (const float*)d_in[3];
    const float* Wz = (const float*)d_in[4];
    const float* bz = (const float*)d_in[5];
    const float* Vw = (const float*)d_in[6];
    // d_in[7] = vb: constant shift over the softmax axis -> no effect, dropped
    const float* wa = (const float*)d_in[8];
    float* out = (float*)d_out;

    char* ws = (char*)d_ws;
    const size_t bBytes = (size_t)V_DIM * K_HALF * 2;  // 4 MiB per B matrix (bf16)
    uint16_t* wsB1 = (uint16_t*)ws;
    uint16_t* wsB2 = (uint16_t*)(ws + bBytes);

    // u lives in d_out (zero it; GEMM accumulates, softmax finishes in-place)
    hipMemsetAsync(d_out, 0, (size_t)M_DIM * sizeof(float), stream);

    transposeB<<<dim3(K_HALF / 32, V_DIM / 32, 2), 256, 0, stream>>>(Ww, Wz, wsB1, wsB2);

    gemm_kernel<<<dim3((M_DIM / 128) * (V_DIM / 128)), 256, 0, stream>>>(
        hidden, z, wsB1, wsB2, bw, bz, wa, Vw, out);

    softmax_kernel<<<B_DIM, 256, 0, stream>>>(out);
}

// Round 4
// 711.827 us; speedup vs baseline: 1.3968x; 1.3968x over previous
//
#include <hip/hip_runtime.h>
#include <hip/hip_bf16.h>
#include <stdint.h>

#define S_DIM 2048
#define B_DIM 16
#define H2_DIM 2048
#define V_DIM 1024
#define M_DIM (S_DIM * B_DIM)   // 32768
#define K_HALF 2048
#define K_TOT 4096

typedef __attribute__((ext_vector_type(8))) short s16x8;   // 8 bf16 (4 VGPRs) MFMA frag
typedef __attribute__((ext_vector_type(4))) float f32x4;   // MFMA accumulator

// fp32 -> bf16 round-to-nearest-even (scalar, used in transposeB only)
__device__ __forceinline__ uint16_t f2bf(float f) {
    union { float f; uint32_t u; } c; c.f = f;
    uint32_t u = c.u;
    u += 0x7fffu + ((u >> 16) & 1u);
    return (uint16_t)(u >> 16);
}

// pack 2 fp32 -> 2 bf16 (round-to-nearest), 3 VALU ops: 2 adds + 1 v_perm_b32
__device__ __forceinline__ uint32_t pack_bf16_rn(float a, float b) {
    union { float f; uint32_t u; } ca, cb; ca.f = a; cb.f = b;
    uint32_t ua = ca.u + 0x8000u;
    uint32_t ub = cb.u + 0x8000u;
    return __builtin_amdgcn_perm(ub, ua, 0x07060302u);
}

__device__ __forceinline__ float fast_tanh(float x) {
    float e = __expf(2.0f * x);
    return 1.0f - 2.0f / (e + 1.0f);
}

// async global->LDS, 16B per lane. LDS dest is wave-uniform base + lane*16.
__device__ __forceinline__ void gload_lds16(const void* g, void* l) {
    __builtin_amdgcn_global_load_lds(
        (__attribute__((address_space(1))) void*)(uintptr_t)g,
        (__attribute__((address_space(3))) void*)(uint32_t)(uintptr_t)l,
        16, 0, 0);
}

// ------------- transpose+convert Ww/Wz [K][V] fp32 -> B^T [V][K] bf16 -------------
__global__ void transposeB(const float* __restrict__ Ww, const float* __restrict__ Wz,
                           uint16_t* __restrict__ B1, uint16_t* __restrict__ B2) {
    __shared__ float tile[32][33];
    const float* src = blockIdx.z ? Wz : Ww;
    uint16_t* dst = blockIdx.z ? B2 : B1;
    int k0 = blockIdx.x * 32, v0 = blockIdx.y * 32;
    int tv = threadIdx.x & 31, tk = threadIdx.x >> 5;  // tk in 0..7
#pragma unroll
    for (int r = 0; r < 4; r++) {
        int k = tk * 4 + r;
        tile[k][tv] = src[(size_t)(k0 + k) * V_DIM + v0 + tv];
    }
    __syncthreads();
#pragma unroll
    for (int r = 0; r < 4; r++) {
        int v = tk * 4 + r;
        dst[(size_t)(v0 + v) * K_HALF + k0 + tv] = f2bf(tile[tv][v]);
    }
}

// ---------------------------------- fused GEMM ----------------------------------
// 128(m) x 256(n) tile, 4 waves 2x2 (64m x 128n each). Software-pipelined K-loop:
//   A(s+1) fp32 global->regs prefetched one step early, packed to bf16 into LDS
//   at the top of step s+1; B bf16 double-buffered in LDS via async DMA that
//   stays IN FLIGHT across the barrier (raw s_barrier + manual vmcnt(16), never 0).
// Epilogue: u[m] += sum_n tanh(C[m,n]+bias[n]) * Vw[n]
__global__ __launch_bounds__(256, 2) void gemm_kernel(
    const float* __restrict__ F1, const float* __restrict__ F2,
    const uint16_t* __restrict__ B1, const uint16_t* __restrict__ B2,
    const float* __restrict__ bw, const float* __restrict__ bz,
    const float* __restrict__ wa_p, const float* __restrict__ Vw,
    float* __restrict__ u) {
    __shared__ __align__(16) uint16_t lA[128 * 64];      // 16 KB, single buffer
    __shared__ __align__(16) uint16_t lB[2][256 * 64];   // 2 x 32 KB double buffer

    const int tid = threadIdx.x;
    const int lane = tid & 63;
    const int wv = tid >> 6;                      // wave 0..3, 2x2 grid
    const int wm = (wv >> 1) * 64, wn = (wv & 1) * 128;
    // XCD swizzle: the 4 n-tiles of an m-tile land on the same XCD (id mod 8),
    // spaced 8 apart in dispatch order -> A K-slices stay L2/L3-warm.
    const int id = blockIdx.x;                    // grid = 1024
    const int nBase = ((id >> 3) & 3) * 256;
    const int mBase = ((id & 7) + ((id >> 5) << 3)) * 128;
    const int lr = lane >> 3;                     // row within 8-row staging group
    const int lc = lane & 7;                      // LDS chunk slot
    const int cg = lc ^ lr;                       // swizzled global chunk
    const int col = lane & 15, quad = lane >> 4;

    f32x4 acc[4][8] = {};

    // staging base pointers (this thread's fixed row/chunk assignment)
    const float* aRow[2];
    const uint16_t* bRow[2];
    {
        const size_t aoff = (size_t)(mBase + wv * 32 + lr) * K_HALF + cg * 8;
        aRow[0] = F1 + aoff; aRow[1] = F2 + aoff;
        const size_t boff = (size_t)(nBase + wv * 64 + lr) * K_HALF + cg * 8;
        bRow[0] = B1 + boff; bRow[1] = B2 + boff;
    }

    float4 ar[4][2];   // A prefetch registers (one step ahead)

    auto loadA = [&](int kb) {
        const float* base = aRow[kb >> 11] + (kb & (K_HALF - 1));
#pragma unroll
        for (int j = 0; j < 4; j++) {
            const float* gp = base + (size_t)(j * 8) * K_HALF;
            ar[j][0] = ((const float4*)gp)[0];
            ar[j][1] = ((const float4*)gp)[1];
        }
    };
    auto issueB = [&](int kb, int p) {
        const uint16_t* base = bRow[kb >> 11] + (kb & (K_HALF - 1));
#pragma unroll
        for (int j = 0; j < 8; j++)
            gload_lds16(base + (size_t)(j * 8) * K_HALF, &lB[p][(wv * 64 + j * 8) * 64]);
    };

    // prologue: prefetch step 0
    loadA(0);
    issueB(0, 0);

#pragma unroll 1
    for (int s = 0; s < 64; s++) {
        const int p = s & 1;

        // stage A(s): pack last step's prefetch regs -> LDS (implicit wait vmcnt(8))
#pragma unroll
        for (int j = 0; j < 4; j++) {
            uint4 w = make_uint4(pack_bf16_rn(ar[j][0].x, ar[j][0].y),
                                 pack_bf16_rn(ar[j][0].z, ar[j][0].w),
                                 pack_bf16_rn(ar[j][1].x, ar[j][1].y),
                                 pack_bf16_rn(ar[j][1].z, ar[j][1].w));
            *(uint4*)&lA[(wv * 32 + j * 8 + lr) * 64 + lc * 8] = w;
        }

        if (s < 63) {
            const int kb2 = (s + 1) * 64;
            loadA(kb2);            // A(s+1) -> regs   (8 loads, stay in flight)
            issueB(kb2, p ^ 1);    // B(s+1) -> LDS    (8 DMA,  stay in flight)
            // barrier1: drain exactly A(s)+B(s) (older than the 16 newest), keep
            // the s+1 prefetch flying across the barrier. lgkm: my ds_writes.
            asm volatile("s_waitcnt vmcnt(16) lgkmcnt(0)\n\ts_barrier" ::: "memory");
        } else {
            asm volatile("s_waitcnt vmcnt(0) lgkmcnt(0)\n\ts_barrier" ::: "memory");
        }

        const uint16_t* lb = lB[p];
#pragma unroll
        for (int kk = 0; kk < 2; kk++) {
            s16x8 af[4], bf[8];
            const int cidx = kk * 4 + quad;
#pragma unroll
            for (int i = 0; i < 4; i++) {
                int m = wm + i * 16 + col;
                af[i] = *(const s16x8*)&lA[m * 64 + ((cidx ^ (m & 7)) << 3)];
            }
#pragma unroll
            for (int j = 0; j < 8; j++) {
                int n = wn + j * 16 + col;
                bf[j] = *(const s16x8*)&lb[n * 64 + ((cidx ^ (n & 7)) << 3)];
            }
#pragma unroll
            for (int i = 0; i < 4; i++)
#pragma unroll
                for (int j = 0; j < 8; j++)
                    acc[i][j] = __builtin_amdgcn_mfma_f32_16x16x32_bf16(af[i], bf[j], acc[i][j], 0, 0, 0);
        }
        // barrier2: all waves done reading lA / lB[p] (frag reads lgkm-complete at
        // MFMA use). No vmcnt drain — s+1 prefetch stays outstanding.
        asm volatile("s_barrier" ::: "memory");
    }

    // ---- fused epilogue: bias + tanh + Vw-dot, reduce 128 n-cols -> u[m] ----
    const float wa05 = wa_p[0] * 0.5f;
    float biasv[8], vwv[8];
#pragma unroll
    for (int j = 0; j < 8; j++) {
        int n = nBase + wn + j * 16 + col;
        biasv[j] = bw[n] + bz[n] + wa05;
        vwv[j] = Vw[n];
    }
#pragma unroll
    for (int i = 0; i < 4; i++) {
#pragma unroll
        for (int r = 0; r < 4; r++) {
            float sv = 0.f;
#pragma unroll
            for (int j = 0; j < 8; j++) {
                float xv = acc[i][j][r] + biasv[j];
                sv += fast_tanh(xv) * vwv[j];
            }
            // reduce across the 16 n-cols held by this quad group (D: col=lane&15)
            sv += __shfl_xor(sv, 8);
            sv += __shfl_xor(sv, 4);
            sv += __shfl_xor(sv, 2);
            sv += __shfl_xor(sv, 1);
            if (col == 0)
                atomicAdd(&u[mBase + wm + i * 16 + quad * 4 + r], sv);
        }
    }
}

// ------------------- softmax over S per batch, in-place on u=d_out -------------------
__global__ void softmax_kernel(float* __restrict__ u) {
    const int b = blockIdx.x;
    const int t = threadIdx.x;  // 256 threads, 8 s-values each
    __shared__ float redm[4], reds[4];
    float v[8];
    float mx = -1e30f;
#pragma unroll
    for (int k = 0; k < 8; k++) {
        v[k] = u[(size_t)(t + k * 256) * B_DIM + b];
        mx = fmaxf(mx, v[k]);
    }
#pragma unroll
    for (int off = 32; off >= 1; off >>= 1) mx = fmaxf(mx, __shfl_xor(mx, off));
    if ((t & 63) == 0) redm[t >> 6] = mx;
    __syncthreads();
    mx = fmaxf(fmaxf(redm[0], redm[1]), fmaxf(redm[2], redm[3]));
    float s = 0.f;
#pragma unroll
    for (int k = 0; k < 8; k++) {
        v[k] = __expf(v[k] - mx);
        s += v[k];
    }
#pragma unroll
    for (int off = 32; off >= 1; off >>= 1) s += __shfl_xor(s, off);
    if ((t & 63) == 0) reds[t >> 6] = s;
    __syncthreads();
    s = reds[0] + reds[1] + reds[2] + reds[3];
    float inv = 1.0f / s;
#pragma unroll
    for (int k = 0; k < 8; k++)
        u[(size_t)(t + k * 256) * B_DIM + b] = v[k] * inv;
}

extern "C" void kernel_launch(void* const* d_in, const int* in_sizes, int n_in,
                              void* d_out, int out_size, void* d_ws, size_t ws_size,
                              hipStream_t stream) {
    const float* hidden = (const float*)d_in[0];
    const float* z = (const float*)d_in[1];
    const float* Ww = (const float*)d_in[2];
    const float* bw = (const float*)d_in[3];
    const float* Wz = (const float*)d_in[4];
    const float* bz = (const float*)d_in[5];
    const float* Vw = (const float*)d_in[6];
    // d_in[7] = vb: constant shift over the softmax axis -> no effect, dropped
    const float* wa = (const float*)d_in[8];
    float* out = (float*)d_out;

    char* ws = (char*)d_ws;
    const size_t bBytes = (size_t)V_DIM * K_HALF * 2;  // 4 MiB per B matrix (bf16)
    uint16_t* wsB1 = (uint16_t*)ws;
    uint16_t* wsB2 = (uint16_t*)(ws + bBytes);

    // u lives in d_out (zero it; GEMM accumulates, softmax finishes in-place)
    hipMemsetAsync(d_out, 0, (size_t)M_DIM * sizeof(float), stream);

    transposeB<<<dim3(K_HALF / 32, V_DIM / 32, 2), 256, 0, stream>>>(Ww, Wz, wsB1, wsB2);

    gemm_kernel<<<dim3((M_DIM / 128) * (V_DIM / 256)), 256, 0, stream>>>(
        hidden, z, wsB1, wsB2, bw, bz, wa, Vw, out);

    softmax_kernel<<<B_DIM, 256, 0, stream>>>(out);
}